// Round 7
// baseline (240.164 us; speedup 1.0000x reference)
//
#include <hip/hip_runtime.h>
#include <hip/hip_bf16.h>

// ModalAttention fused pipeline, MI355X (gfx950).
//
// Math: attn/|global_min| followed by L2-normalize cancels any positive
// per-tensor scale (incl. /sqrt(h)) -> softmax input = s_row/||s_row||_2,
// s = q.k. No global-min reduction needed.
//
// Round 7: qkv -> m201-style fine-grained phases. Each BK=32 subtile is
// split into two half-phases of 16 MFMA each, with reads+stage issued
// BEFORE the leading barrier (they hide under other waves' MFMA between
// barriers) and MFMA isolated between two barriers under setprio(1):
//   H1: read av0-3+bv (8 b128); stage 2 A-loads; bar; lgkm0; 16 MFMA; bar
//   H2: read av4-7 (4 b128); stage 2 B-loads+advance; bar; lgkm0;
//       16 MFMA; vmcnt(8|4|0); bar
// Counted vmcnt once per subtile (steady 8 outstanding = 2 subtiles in
// flight); ring-4 slots, XOR swizzle, staging identical to round 5
// (verified correct, 0 bank conflicts). Math order unchanged -> output
// bit-identical to rounds 4-6.

typedef __bf16 bf16x8 __attribute__((ext_vector_type(8)));
typedef float f32x4 __attribute__((ext_vector_type(4)));

struct alignas(16) US8 { unsigned short s[8]; };
struct alignas(8)  US4 { unsigned short s[4]; };

// ---------------- workspace layout (bytes) ----------------
#define WS_XB   0ull                        // data bf16  [16384][1024]  33.55MB
#define WS_WB   33554432ull                 // wq,wk,wv bf16 [3][1024][1024] 6.29MB
#define WS_Q    39845888ull                 // Q bf16 [16384][1024] 33.55MB
#define WS_K    73400320ull                 // K bf16 [16384][1024] 33.55MB
#define WS_VT   106954752ull                // V^T bf16 [32][1024][512] 33.55MB
#define WS_S    140509184ull                // S bf16 [16384][512] 16.78MB
#define WS_P    157286400ull                // P bf16 [16384][512] 16.78MB
#define WS_NEED 174063616ull
#define WS_O    WS_Q                        // O bf16 [16384][1024] 33.55MB reuses Q

__device__ __forceinline__ unsigned short f32_to_bf16(float f) {
  unsigned int u = __builtin_bit_cast(unsigned int, f);
  u += 0x7fffu + ((u >> 16) & 1u);            // round-to-nearest-even
  return (unsigned short)(u >> 16);
}
__device__ __forceinline__ float bf16_to_f32(unsigned short h) {
  return __builtin_bit_cast(float, (unsigned int)h << 16);
}

__device__ __forceinline__ void gload_lds16(const void* g, void* lds) {
  __builtin_amdgcn_global_load_lds(
      (const __attribute__((address_space(1))) unsigned int*)g,
      (__attribute__((address_space(3))) unsigned int*)lds, 16, 0, 0);
}

__device__ __forceinline__ float wave_sum(float v) {
#pragma unroll
  for (int off = 32; off > 0; off >>= 1) v += __shfl_xor(v, off);
  return v;
}
__device__ __forceinline__ float wave_max(float v) {
#pragma unroll
  for (int off = 32; off > 0; off >>= 1) v = fmaxf(v, __shfl_xor(v, off));
  return v;
}

// ---------------- f32 -> bf16 cast ----------------
__global__ __launch_bounds__(256) void cvt_f32_bf16(const float* __restrict__ src,
                                                    unsigned short* __restrict__ dst,
                                                    int n8) {
  int i = blockIdx.x * 256 + threadIdx.x;
  if (i >= n8) return;
  const float4* sp = (const float4*)(src + (size_t)i * 8);
  float4 a = sp[0], b = sp[1];
  US8 u;
  u.s[0] = f32_to_bf16(a.x); u.s[1] = f32_to_bf16(a.y);
  u.s[2] = f32_to_bf16(a.z); u.s[3] = f32_to_bf16(a.w);
  u.s[4] = f32_to_bf16(b.x); u.s[5] = f32_to_bf16(b.y);
  u.s[6] = f32_to_bf16(b.z); u.s[7] = f32_to_bf16(b.w);
  *(US8*)(dst + (size_t)i * 8) = u;
}

// ============ QKV: 256x256 tile, 4-slot BK=32 ring, N=3072 ============
// M=16384, K=1024 (32 subtiles). 768 blocks x 512 threads (8 waves, 2Mx4N).
// LDS: 4 slots x (A[256][32] + B[256][32]) bf16 = 128 KiB, XOR-swizzled:
//   LDS chunk' = src chunk ^ ((row>>1)&3)  (16B chunks, 4 per 64B row)
__global__ __launch_bounds__(512, 2) void qkv_8ph(
    const unsigned short* __restrict__ Xb, const unsigned short* __restrict__ Wb,
    unsigned short* __restrict__ Q, unsigned short* __restrict__ Kb,
    unsigned short* __restrict__ Vt) {
  __shared__ unsigned short sm[4][16384];   // slot: A bytes [0,16384), B [16384,32768)

  const int tid = threadIdx.x;
  const int w = tid >> 6, lane = tid & 63;
  const int wm = w >> 2, wn = w & 3;
  const int lr = lane & 15, lk4 = lane >> 4;

  // bijective XCD-chunked swizzle: 768 blocks, 96 per XCD
  const int bid = blockIdx.x;
  const int wg = (bid & 7) * 96 + (bid >> 3);
  const int bm = wg / 12, bn = wg % 12;

  const char* Ag = (const char*)(Xb + (size_t)bm * 256 * 1024);
  const char* Bg = (const char*)(Wb + (size_t)bn * 256 * 1024);

  // stage: dest chunk id c = tid + j*512 -> row r=(tid>>2)+j*128, chunk'=tid&3.
  // source chunk = chunk' ^ ((r>>1)&3) = (lane&3) ^ ((lane>>3)&3) (fixed/lane)
  const int srow = w * 16 + (lane >> 2);
  const int schunk = ((lane & 3) ^ ((lane >> 3) & 3)) * 16;
  const char* gA0 = Ag + (size_t)srow * 2048 + schunk;
  const char* gA1 = gA0 + 128 * 2048;
  const char* gB0 = Bg + (size_t)srow * 2048 + schunk;
  const char* gB1 = gB0 + 128 * 2048;

  // read: row = base + lr (base components = 0 mod 8), need src chunk lk4
  //   -> LDS chunk = lk4 ^ ((row>>1)&3) = lk4 ^ ((lr>>1)&3)
  const int wmbase = wm * 128 + lr;   // A row base (+ m*16)
  const int wnbase = wn * 64 + lr;    // B row base (+ n*16)
  const int rk = (lk4 ^ ((lr >> 1) & 3)) * 16;  // swizzled k-byte in 64B row

  f32x4 acc[8][4] = {};
  bf16x8 av[8], bv[4];

  // prologue staging: 4 loads (A,A,B,B) for current subtile, advance 64B.
#define QKV_STAGE4(SI)                                                        \
  do {                                                                        \
    char* dA = (char*)sm[SI] + w * 1024;                                      \
    gload_lds16(gA0, dA);                                                     \
    gload_lds16(gA1, dA + 8192);                                              \
    gload_lds16(gB0, dA + 16384);                                             \
    gload_lds16(gB1, dA + 24576);                                             \
    gA0 += 64; gA1 += 64; gB0 += 64; gB1 += 64;                               \
  } while (0)

#define QKV_MFMA_H(MB)                                                        \
  __builtin_amdgcn_s_setprio(1);                                              \
  _Pragma("unroll") for (int mm = 0; mm < 4; ++mm)                            \
      _Pragma("unroll") for (int nn = 0; nn < 4; ++nn)                        \
          acc[(MB) + mm][nn] = __builtin_amdgcn_mfma_f32_16x16x32_bf16(       \
              av[(MB) + mm], bv[nn], acc[(MB) + mm][nn], 0, 0, 0);            \
  __builtin_amdgcn_s_setprio(0);

  // H1: read m0-3 frags + B frags of SLOT; stage 2 A-loads of SLOT+3.
#define QKV_H1(SLOT, DO_STAGE)                                                \
  do {                                                                        \
    const char* sA = (const char*)sm[SLOT];                                   \
    const char* sB = sA + 16384;                                              \
    _Pragma("unroll") for (int m = 0; m < 4; ++m)                             \
        av[m] = *(const bf16x8*)(sA + ((wmbase + m * 16) << 6) + rk);         \
    _Pragma("unroll") for (int n = 0; n < 4; ++n)                             \
        bv[n] = *(const bf16x8*)(sB + ((wnbase + n * 16) << 6) + rk);         \
    if (DO_STAGE) {                                                           \
      char* dA = (char*)sm[(SLOT + 3) & 3] + w * 1024;                        \
      gload_lds16(gA0, dA);                                                   \
      gload_lds16(gA1, dA + 8192);                                            \
    }                                                                         \
    __builtin_amdgcn_sched_barrier(0);                                        \
    __builtin_amdgcn_s_barrier();                                             \
    asm volatile("s_waitcnt lgkmcnt(0)" ::: "memory");                        \
    __builtin_amdgcn_sched_barrier(0);                                        \
    QKV_MFMA_H(0)                                                             \
    __builtin_amdgcn_sched_barrier(0);                                        \
    __builtin_amdgcn_s_barrier();                                             \
  } while (0)

  // H2: read m4-7 frags of SLOT; stage 2 B-loads of SLOT+3 + advance; vmcnt.
#define QKV_H2(SLOT, DO_STAGE, VMASM)                                         \
  do {                                                                        \
    const char* sA = (const char*)sm[SLOT];                                   \
    _Pragma("unroll") for (int m = 4; m < 8; ++m)                             \
        av[m] = *(const bf16x8*)(sA + ((wmbase + m * 16) << 6) + rk);         \
    if (DO_STAGE) {                                                           \
      char* dB = (char*)sm[(SLOT + 3) & 3] + w * 1024 + 16384;                \
      gload_lds16(gB0, dB);                                                   \
      gload_lds16(gB1, dB + 8192);                                            \
      gA0 += 64; gA1 += 64; gB0 += 64; gB1 += 64;                             \
    }                                                                         \
    __builtin_amdgcn_sched_barrier(0);                                        \
    __builtin_amdgcn_s_barrier();                                             \
    asm volatile("s_waitcnt lgkmcnt(0)" ::: "memory");                        \
    __builtin_amdgcn_sched_barrier(0);                                        \
    QKV_MFMA_H(4)                                                             \
    __builtin_amdgcn_sched_barrier(0);                                        \
    VMASM;                                                                    \
    __builtin_amdgcn_s_barrier();                                             \
  } while (0)

#define VMW8 asm volatile("s_waitcnt vmcnt(8)" ::: "memory")
#define VMW4 asm volatile("s_waitcnt vmcnt(4)" ::: "memory")
#define VMW0 asm volatile("s_waitcnt vmcnt(0)" ::: "memory")
#define VMNOP (void)0

  // prologue: stage subtiles 0,1,2 into slots 0,1,2 (12 loads in flight)
  QKV_STAGE4(0);
  QKV_STAGE4(1);
  QKV_STAGE4(2);
  asm volatile("s_waitcnt vmcnt(8)" ::: "memory");   // subtile 0 landed
  __builtin_amdgcn_s_barrier();
  __builtin_amdgcn_sched_barrier(0);

  // main: subtiles 0..27 (7 iters x 4), each stages subtile s+3
  for (int i = 0; i < 7; ++i) {
    QKV_H1(0, 1); QKV_H2(0, 1, VMW8);
    QKV_H1(1, 1); QKV_H2(1, 1, VMW8);
    QKV_H1(2, 1); QKV_H2(2, 1, VMW8);
    QKV_H1(3, 1); QKV_H2(3, 1, VMW8);
  }
  // tail: s=28 stages subtile 31; 29/30/31 drain (vm 4/0/none)
  QKV_H1(0, 1); QKV_H2(0, 1, VMW8);   // s=28
  QKV_H1(1, 0); QKV_H2(1, 0, VMW4);   // s=29
  QKV_H1(2, 0); QKV_H2(2, 0, VMW0);   // s=30
  QKV_H1(3, 0); QKV_H2(3, 0, VMNOP);  // s=31

#undef QKV_H1
#undef QKV_H2
#undef QKV_MFMA_H
#undef QKV_STAGE4

  // epilogue: C fragment (row = base + (lane>>4)*4 + i, col = base + (lane&15))
  const int cr = lk4 << 2;
  const int z = bn >> 2;                       // 0=Q 1=K 2=V
  const int gr0 = bm * 256 + wm * 128;
  const int gc0 = (bn & 3) * 256 + wn * 64;
  if (z < 2) {
    unsigned short* C = (z == 0) ? Q : Kb;
#pragma unroll
    for (int m = 0; m < 8; ++m)
#pragma unroll
      for (int n = 0; n < 4; ++n)
#pragma unroll
        for (int i = 0; i < 4; ++i)
          C[(size_t)(gr0 + m * 16 + cr + i) * 1024 + (gc0 + n * 16 + lr)] =
              f32_to_bf16(acc[m][n][i]);
  } else {
    // Vt[b][d][t] = V[b*512+t][d]; 4 consecutive t per lane -> 8B store
#pragma unroll
    for (int m = 0; m < 8; ++m) {
      const int gr = gr0 + m * 16 + cr;
      const int b = gr >> 9, tt = gr & 511;
#pragma unroll
      for (int n = 0; n < 4; ++n) {
        const int d = gc0 + n * 16 + lr;
        US4 u;
        u.s[0] = f32_to_bf16(acc[m][n][0]);
        u.s[1] = f32_to_bf16(acc[m][n][1]);
        u.s[2] = f32_to_bf16(acc[m][n][2]);
        u.s[3] = f32_to_bf16(acc[m][n][3]);
        *(US4*)(Vt + ((size_t)b * 1024 + d) * 512 + tt) = u;
      }
    }
  }
}

// ---------------- shared BT-GEMM core (m97 structure + XOR swizzle) ----------
__device__ __forceinline__ void gemm_bt_core(const unsigned short* __restrict__ A,
                                             const unsigned short* __restrict__ B,
                                             int lda, int ldb, int K,
                                             unsigned short* As, unsigned short* Bs,
                                             f32x4 acc[4][4]) {
  const int tid = threadIdx.x;
  const int w = tid >> 6, lane = tid & 63;
  const int wr = w >> 1, wc = w & 1;
  const int lr = lane & 15;
  // read: src chunk (lane>>4) at row base+lr -> LDS chunk ^ ((lr>>1)&3)
  const int lk = (((lane >> 4) ^ ((lr >> 1) & 3))) << 3;
  // stage: dest chunk id c=(i<<6)+lane -> row i*16+(lane>>2), chunk'=lane&3;
  // source chunk = (lane&3) ^ ((lane>>3)&3)
  const int k8 = (((lane & 3) ^ ((lane >> 3) & 3))) << 3;

  for (int kk = 0; kk < K; kk += 32) {
#pragma unroll
    for (int j = 0; j < 2; ++j) {
      const int i = (w << 1) + j;            // 0..7 wave-load id
      const int c = (i << 6) + lane;         // 16B chunk id, 512 per tile
      const int r = c >> 2;                  // tile row 0..127
      gload_lds16(A + (size_t)r * lda + kk + k8, As + (i << 9));
      gload_lds16(B + (size_t)r * ldb + kk + k8, Bs + (i << 9));
    }
    __syncthreads();                         // drains vmcnt for all waves
    bf16x8 av[4], bv[4];
#pragma unroll
    for (int m = 0; m < 4; ++m)
      av[m] = *(const bf16x8*)(As + (((wr << 6) + (m << 4) + lr) << 5) + lk);
#pragma unroll
    for (int n = 0; n < 4; ++n)
      bv[n] = *(const bf16x8*)(Bs + (((wc << 6) + (n << 4) + lr) << 5) + lk);
#pragma unroll
    for (int m = 0; m < 4; ++m)
#pragma unroll
      for (int n = 0; n < 4; ++n)
        acc[m][n] = __builtin_amdgcn_mfma_f32_16x16x32_bf16(av[m], bv[n], acc[m][n], 0, 0, 0);
    __syncthreads();
  }
}

// ---------------- S = Q K^T per batch (bf16 out) ----------------
__global__ __launch_bounds__(256) void s_gemm(const unsigned short* __restrict__ Q,
                                              const unsigned short* __restrict__ Kb,
                                              unsigned short* __restrict__ S) {
  __shared__ unsigned short As[4096];
  __shared__ unsigned short Bs[4096];
  const int bn = blockIdx.x, bm = blockIdx.y, b = blockIdx.z;
  const unsigned short* A = Q + ((size_t)b * 512 + bm * 128) * 1024;
  const unsigned short* B = Kb + ((size_t)b * 512 + bn * 128) * 1024;
  f32x4 acc[4][4] = {};
  gemm_bt_core(A, B, 1024, 1024, 1024, As, Bs, acc);

  const int tid = threadIdx.x;
  const int w = tid >> 6, lane = tid & 63;
  const int wr = w >> 1, wc = w & 1;
  const int cr = (lane >> 4) << 2;
  const int cc = lane & 15;
  unsigned short* Cp = S + (size_t)b * 262144;
  const int rbase = bm * 128 + wr * 64;
  const int cbase = bn * 128 + wc * 64;
#pragma unroll
  for (int m = 0; m < 4; ++m)
#pragma unroll
    for (int n = 0; n < 4; ++n)
#pragma unroll
      for (int i = 0; i < 4; ++i)
        Cp[(size_t)(rbase + m * 16 + cr + i) * 512 + (cbase + n * 16 + cc)] =
            f32_to_bf16(acc[m][n][i]);
}

// ---------------- row L2-normalize + softmax; write attn f32 + P bf16 -------
__global__ __launch_bounds__(256) void softmax_rows(const unsigned short* __restrict__ S,
                                                    float* __restrict__ out,
                                                    unsigned short* __restrict__ P) {
  const int w = threadIdx.x >> 6, lane = threadIdx.x & 63;
  const int r = blockIdx.x * 4 + w;          // global row 0..16383
  const int b = r >> 9, s = r & 511;
  US8 v = *(const US8*)(S + (size_t)r * 512 + lane * 8);
  float x[8];
#pragma unroll
  for (int i = 0; i < 8; ++i) x[i] = bf16_to_f32(v.s[i]);
  float ss = 0.f;
#pragma unroll
  for (int i = 0; i < 8; ++i) ss += x[i] * x[i];
  ss = wave_sum(ss);
  const float inv = 1.0f / fmaxf(sqrtf(ss), 1e-12f);
  float mx = -1e30f;
#pragma unroll
  for (int i = 0; i < 8; ++i) { x[i] *= inv; mx = fmaxf(mx, x[i]); }
  mx = wave_max(mx);
  float se = 0.f;
#pragma unroll
  for (int i = 0; i < 8; ++i) { x[i] = __expf(x[i] - mx); se += x[i]; }
  se = wave_sum(se);
  const float rs = 1.0f / se;
#pragma unroll
  for (int i = 0; i < 8; ++i) x[i] *= rs;

  float* op = out + (size_t)b * 786432 + 524288 + (size_t)s * 512 + lane * 8;
  float4 o0 = {x[0], x[1], x[2], x[3]};
  float4 o1 = {x[4], x[5], x[6], x[7]};
  *(float4*)op = o0;
  *(float4*)(op + 4) = o1;
  US8 u;
#pragma unroll
  for (int i = 0; i < 8; ++i) u.s[i] = f32_to_bf16(x[i]);
  *(US8*)(P + (size_t)r * 512 + lane * 8) = u;
}

// ---------------- O = P * V (via Vt, BT layout), bf16 out ----------------
__global__ __launch_bounds__(256) void pv_gemm(const unsigned short* __restrict__ P,
                                               const unsigned short* __restrict__ Vt,
                                               unsigned short* __restrict__ O) {
  __shared__ unsigned short As[4096];
  __shared__ unsigned short Bs[4096];
  const int bn = blockIdx.x, bm = blockIdx.y, b = blockIdx.z;
  const unsigned short* A = P + ((size_t)b * 512 + bm * 128) * 512;
  const unsigned short* B = Vt + ((size_t)b * 1024 + bn * 128) * 512;
  f32x4 acc[4][4] = {};
  gemm_bt_core(A, B, 512, 512, 512, As, Bs, acc);

  const int tid = threadIdx.x;
  const int w = tid >> 6, lane = tid & 63;
  const int wr = w >> 1, wc = w & 1;
  const int cr = (lane >> 4) << 2;
  const int cc = lane & 15;
  const int grow = b * 512 + bm * 128 + wr * 64;
  const int cbase = bn * 128 + wc * 64;
#pragma unroll
  for (int m = 0; m < 4; ++m)
#pragma unroll
    for (int n = 0; n < 4; ++n)
#pragma unroll
      for (int i = 0; i < 4; ++i)
        O[(size_t)(grow + m * 16 + cr + i) * 1024 + (cbase + n * 16 + cc)] =
            f32_to_bf16(acc[m][n][i]);
}

// ---------------- residual + LayerNorm, wave per row ----------------
__global__ __launch_bounds__(256) void ln_rows(const unsigned short* __restrict__ O,
                                               const unsigned short* __restrict__ Xb,
                                               const float* __restrict__ gamma,
                                               const float* __restrict__ beta,
                                               float* __restrict__ out) {
  const int w = threadIdx.x >> 6, lane = threadIdx.x & 63;
  const int r = blockIdx.x * 4 + w;
  const int b = r >> 9, s = r & 511;
  const unsigned short* orow = O + (size_t)r * 1024;
  const unsigned short* drow = Xb + (size_t)r * 1024;
  float x[16];
  float sm = 0.f, sq = 0.f;
#pragma unroll
  for (int j = 0; j < 4; ++j) {
    const int col = j * 256 + lane * 4;
    US4 o4 = *(const US4*)(orow + col);
    US4 d4 = *(const US4*)(drow + col);
    x[j * 4 + 0] = bf16_to_f32(o4.s[0]) + bf16_to_f32(d4.s[0]);
    x[j * 4 + 1] = bf16_to_f32(o4.s[1]) + bf16_to_f32(d4.s[1]);
    x[j * 4 + 2] = bf16_to_f32(o4.s[2]) + bf16_to_f32(d4.s[2]);
    x[j * 4 + 3] = bf16_to_f32(o4.s[3]) + bf16_to_f32(d4.s[3]);
  }
#pragma unroll
  for (int i = 0; i < 16; ++i) { sm += x[i]; sq += x[i] * x[i]; }
  sm = wave_sum(sm);
  sq = wave_sum(sq);
  const float mean = sm * (1.0f / 1024.0f);
  const float var = sq * (1.0f / 1024.0f) - mean * mean;
  const float rstd = rsqrtf(var + 1e-6f);
  float* op = out + (size_t)b * 786432 + (size_t)s * 1024;
#pragma unroll
  for (int j = 0; j < 4; ++j) {
    const int col = j * 256 + lane * 4;
    float4 g4 = *(const float4*)(gamma + col);
    float4 b4 = *(const float4*)(beta + col);
    float4 y;
    y.x = (x[j * 4 + 0] - mean) * rstd * g4.x + b4.x;
    y.y = (x[j * 4 + 1] - mean) * rstd * g4.y + b4.y;
    y.z = (x[j * 4 + 2] - mean) * rstd * g4.z + b4.z;
    y.w = (x[j * 4 + 3] - mean) * rstd * g4.w + b4.w;
    *(float4*)(op + col) = y;
  }
}

extern "C" void kernel_launch(void* const* d_in, const int* in_sizes, int n_in,
                              void* d_out, int out_size, void* d_ws, size_t ws_size,
                              hipStream_t stream) {
  const float* data  = (const float*)d_in[0];
  const float* wq    = (const float*)d_in[1];
  const float* wk    = (const float*)d_in[2];
  const float* wv    = (const float*)d_in[3];
  const float* gamma = (const float*)d_in[4];
  const float* beta  = (const float*)d_in[5];
  float* out = (float*)d_out;
  char* ws = (char*)d_ws;
  if (ws_size < WS_NEED) return;

  unsigned short* Xb = (unsigned short*)(ws + WS_XB);
  unsigned short* Wb = (unsigned short*)(ws + WS_WB);
  unsigned short* Q  = (unsigned short*)(ws + WS_Q);
  unsigned short* Kb = (unsigned short*)(ws + WS_K);
  unsigned short* Vt = (unsigned short*)(ws + WS_VT);
  unsigned short* S  = (unsigned short*)(ws + WS_S);
  unsigned short* P  = (unsigned short*)(ws + WS_P);
  unsigned short* O  = (unsigned short*)(ws + WS_O);

  cvt_f32_bf16<<<8192, 256, 0, stream>>>(data, Xb, 2097152);
  cvt_f32_bf16<<<512, 256, 0, stream>>>(wq, Wb, 131072);
  cvt_f32_bf16<<<512, 256, 0, stream>>>(wk, Wb + 1048576, 131072);
  cvt_f32_bf16<<<512, 256, 0, stream>>>(wv, Wb + 2097152, 131072);
  qkv_8ph<<<768, 512, 0, stream>>>(Xb, Wb, Q, Kb, Vt);
  s_gemm<<<dim3(4, 4, 32), 256, 0, stream>>>(Q, Kb, S);
  softmax_rows<<<4096, 256, 0, stream>>>(S, out, P);
  pv_gemm<<<dim3(8, 4, 32), 256, 0, stream>>>(P, Vt, O);
  ln_rows<<<4096, 256, 0, stream>>>(O, Xb, gamma, beta, out);
}

// Round 8
// 226.158 us; speedup vs baseline: 1.0619x; 1.0619x over previous
//
#include <hip/hip_runtime.h>
#include <hip/hip_bf16.h>

// ModalAttention fused pipeline, MI355X (gfx950).
//
// Math: attn/|global_min| followed by L2-normalize cancels any positive
// per-tensor scale (incl. /sqrt(h)) -> softmax input = s_row/||s_row||_2,
// s = q.k. No global-min reduction needed.
//
// Round 8: QKV projection in fp8 e4m3 with v_mfma_f32_16x16x128_f8f6f4
// (non-scaled asm form, cbsz/blgp=0 => fp8/fp8). Halves LDS bytes/FLOP,
// halves staging traffic, 8 subtiles of K=128 instead of 32 of K=32
// (4x fewer barriers), 2x MFMA rate. fp8 error on S (~4% rel) is crushed
// by L2-norm+softmax (softmax inputs std~0.044 -> attn err ~1e-5); V-path
// error ~0.002 pre-LN. Q/K/V outputs remain bf16; the rest of the
// pipeline is the proven round-5/6 code (0 bank conflicts, PASS 238us).

typedef __bf16 bf16x8 __attribute__((ext_vector_type(8)));
typedef float f32x4 __attribute__((ext_vector_type(4)));
typedef int i32x4v __attribute__((ext_vector_type(4)));
typedef int i32x8v __attribute__((ext_vector_type(8)));

struct alignas(16) US8 { unsigned short s[8]; };
struct alignas(8)  US4 { unsigned short s[4]; };

// ---------------- workspace layout (bytes) ----------------
#define WS_XB   0ull                        // data bf16 [16384][1024] 33.55MB (ln residual)
#define WS_XF8  33554432ull                 // data fp8  [16384][1024] 16.78MB
#define WS_WF8  50331648ull                 // wq,wk,wv fp8 [3][1024][1024] 3.15MB
#define WS_Q    53477376ull                 // Q bf16 [16384][1024] 33.55MB
#define WS_K    87031808ull                 // K bf16 [16384][1024] 33.55MB
#define WS_VT   120586240ull                // V^T bf16 [32][1024][512] 33.55MB
#define WS_S    154140672ull                // S bf16 [16384][512] 16.78MB
#define WS_P    170917888ull                // P bf16 [16384][512] 16.78MB
#define WS_NEED 187695104ull
#define WS_O    WS_Q                        // O bf16 reuses Q (dead after s_gemm)

__device__ __forceinline__ unsigned short f32_to_bf16(float f) {
  unsigned int u = __builtin_bit_cast(unsigned int, f);
  u += 0x7fffu + ((u >> 16) & 1u);            // round-to-nearest-even
  return (unsigned short)(u >> 16);
}
__device__ __forceinline__ float bf16_to_f32(unsigned short h) {
  return __builtin_bit_cast(float, (unsigned int)h << 16);
}

__device__ __forceinline__ void gload_lds16(const void* g, void* lds) {
  __builtin_amdgcn_global_load_lds(
      (const __attribute__((address_space(1))) unsigned int*)g,
      (__attribute__((address_space(3))) unsigned int*)lds, 16, 0, 0);
}

__device__ __forceinline__ float wave_sum(float v) {
#pragma unroll
  for (int off = 32; off > 0; off >>= 1) v += __shfl_xor(v, off);
  return v;
}
__device__ __forceinline__ float wave_max(float v) {
#pragma unroll
  for (int off = 32; off > 0; off >>= 1) v = fmaxf(v, __shfl_xor(v, off));
  return v;
}

__device__ __forceinline__ unsigned int pk_fp8x4(float a, float b, float c, float d) {
  unsigned int v = 0;
  v = __builtin_amdgcn_cvt_pk_fp8_f32(a, b, v, false);  // bytes 0,1
  v = __builtin_amdgcn_cvt_pk_fp8_f32(c, d, v, true);   // bytes 2,3
  return v;
}

// ---------------- data cast: f32 -> bf16 (Xb) + fp8 (Xf8) ----------------
__global__ __launch_bounds__(256) void cvt_data(const float* __restrict__ src,
                                                unsigned short* __restrict__ dstb,
                                                unsigned int* __restrict__ dst8,
                                                int n8) {
  int i = blockIdx.x * 256 + threadIdx.x;
  if (i >= n8) return;
  const float4* sp = (const float4*)(src + (size_t)i * 8);
  float4 a = sp[0], b = sp[1];
  US8 u;
  u.s[0] = f32_to_bf16(a.x); u.s[1] = f32_to_bf16(a.y);
  u.s[2] = f32_to_bf16(a.z); u.s[3] = f32_to_bf16(a.w);
  u.s[4] = f32_to_bf16(b.x); u.s[5] = f32_to_bf16(b.y);
  u.s[6] = f32_to_bf16(b.z); u.s[7] = f32_to_bf16(b.w);
  *(US8*)(dstb + (size_t)i * 8) = u;
  uint2 w;
  w.x = pk_fp8x4(a.x, a.y, a.z, a.w);
  w.y = pk_fp8x4(b.x, b.y, b.z, b.w);
  *(uint2*)(dst8 + (size_t)i * 2) = w;
}

// ---------------- weights cast: f32 -> fp8, 3 matrices ----------------
__global__ __launch_bounds__(256) void cvt_w3(const float* __restrict__ wq,
                                              const float* __restrict__ wk,
                                              const float* __restrict__ wv,
                                              unsigned int* __restrict__ dst8) {
  const int z = blockIdx.y;
  const float* src = (z == 0) ? wq : (z == 1) ? wk : wv;
  int i = blockIdx.x * 256 + threadIdx.x;   // 0..131071 (x8 elems)
  const float4* sp = (const float4*)(src + (size_t)i * 8);
  float4 a = sp[0], b = sp[1];
  uint2 w;
  w.x = pk_fp8x4(a.x, a.y, a.z, a.w);
  w.y = pk_fp8x4(b.x, b.y, b.z, b.w);
  *(uint2*)(dst8 + (size_t)z * 262144 + (size_t)i * 2) = w;
}

// ============ QKV fp8: 256x256 tile, 2-slot BK=128 dbuf, N=3072 ============
// M=16384, K=1024 (8 subtiles of 128). 768 blocks x 512 threads (8 waves 2Mx4N).
// LDS: 2 slots x (A[256][128B] + B[256][128B]) fp8 = 128 KiB.
// XOR swizzle on 16B granules: lds granule = src granule ^ (row&7).
// Phase s (slot=s&1): vmcnt(8); bar; read av0-3+bv (16 b128); lgkm0;
//   16 MFMA(m0-3); read av4-7 (8 b128); lgkm0; bar; stage s+2 -> slot;
//   16 MFMA(m4-7). Counted vmcnt: steady 8 outstanding (1 subtile ahead).
__global__ __launch_bounds__(512, 2) void qkv_mx(
    const unsigned char* __restrict__ Xf8, const unsigned char* __restrict__ Wf8,
    unsigned short* __restrict__ Q, unsigned short* __restrict__ Kb,
    unsigned short* __restrict__ Vt) {
  __shared__ alignas(16) char smc[2][65536];  // slot: A [0,32768), B [32768,65536)

  const int tid = threadIdx.x;
  const int w = tid >> 6, lane = tid & 63;
  const int wm = w >> 2, wn = w & 3;
  const int lr = lane & 15, lk4 = lane >> 4;

  // bijective XCD-chunked swizzle: 768 blocks, 96 per XCD
  const int bid = blockIdx.x;
  const int wg = (bid & 7) * 96 + (bid >> 3);
  const int bm = wg / 12, bn = wg % 12;

  const char* Af8 = (const char*)Xf8 + (size_t)bm * 256 * 1024;
  const char* Bf8 = (const char*)Wf8 + (size_t)bn * 256 * 1024;

  // stage: dest granule c = j*512 + tid -> row = j*64 + w*8 + (lane>>3),
  // granule-in-row = lane&7; src granule = (lane&7) ^ ((lane>>3)&7).
  const int strow = w * 8 + (lane >> 3);
  const int sch = ((lane & 7) ^ ((lane >> 3) & 7)) * 16;
  const char* pA[4];
  const char* pB[4];
#pragma unroll
  for (int j = 0; j < 4; ++j) {
    pA[j] = Af8 + (size_t)(j * 64 + strow) * 1024 + sch;
    pB[j] = Bf8 + (size_t)(j * 64 + strow) * 1024 + sch;
  }

  // read: A row = wm*128 + m*16 + (lane&15), wants granules (lane>>4)*2+{0,1}
  // at lds granule g ^ (row&7), row&7 = lane&7.
  const int rAbase = (wm * 128 + lr) * 128;
  const int rBbase = (wn * 64 + lr) * 128;
  const int g0 = (lane >> 4) * 2;
  const int c0 = ((g0) ^ (lane & 7)) * 16;
  const int c1 = ((g0 + 1) ^ (lane & 7)) * 16;

  f32x4 acc[8][4] = {};

#define QKV_STAGE8(SLOT)                                                      \
  do {                                                                        \
    char* dd = (char*)smc + (SLOT) * 65536 + w * 1024;                        \
    _Pragma("unroll") for (int j = 0; j < 4; ++j)                             \
        gload_lds16(pA[j], dd + j * 8192);                                    \
    _Pragma("unroll") for (int j = 0; j < 4; ++j)                             \
        gload_lds16(pB[j], dd + 32768 + j * 8192);                            \
    _Pragma("unroll") for (int j = 0; j < 4; ++j) { pA[j] += 128; pB[j] += 128; } \
  } while (0)

#define RD8(BASEPTR, ROWB, MIDX)                                              \
  ({                                                                          \
    i32x4v lo_ = *(const i32x4v*)((BASEPTR) + (ROWB) + (MIDX) * 2048 + c0);   \
    i32x4v hi_ = *(const i32x4v*)((BASEPTR) + (ROWB) + (MIDX) * 2048 + c1);   \
    i32x8v r_;                                                                \
    r_[0] = lo_[0]; r_[1] = lo_[1]; r_[2] = lo_[2]; r_[3] = lo_[3];           \
    r_[4] = hi_[0]; r_[5] = hi_[1]; r_[6] = hi_[2]; r_[7] = hi_[3];           \
    r_;                                                                       \
  })

#define MFMA1(MM, NN)                                                         \
  asm("v_mfma_f32_16x16x128_f8f6f4 %0, %1, %2, %0"                            \
      : "+a"(acc[MM][NN]) : "v"(af[MM & 3]), "v"(bf[NN]))

#define QKV_PHASE(SLOT, VM, DO_STAGE)                                         \
  do {                                                                        \
    asm volatile("s_waitcnt vmcnt(" #VM ")" ::: "memory");                    \
    __builtin_amdgcn_s_barrier();                                             \
    __builtin_amdgcn_sched_barrier(0);                                        \
    const char* sA = (const char*)smc + (SLOT) * 65536;                       \
    const char* sB = sA + 32768;                                              \
    i32x8v af[4], bf[4];                                                      \
    _Pragma("unroll") for (int m = 0; m < 4; ++m)                             \
        af[m] = RD8(sA, rAbase, m);                                           \
    _Pragma("unroll") for (int n = 0; n < 4; ++n)                             \
        bf[n] = RD8(sB, rBbase, n);                                           \
    asm volatile("s_waitcnt lgkmcnt(0)" ::: "memory");                        \
    __builtin_amdgcn_sched_barrier(0);                                        \
    __builtin_amdgcn_s_setprio(1);                                            \
    _Pragma("unroll") for (int mm = 0; mm < 4; ++mm)                          \
        _Pragma("unroll") for (int nn = 0; nn < 4; ++nn) MFMA1(mm, nn);       \
    __builtin_amdgcn_s_setprio(0);                                            \
    _Pragma("unroll") for (int m = 0; m < 4; ++m)                             \
        af[m] = RD8(sA, rAbase, m + 4);                                       \
    asm volatile("s_waitcnt lgkmcnt(0)" ::: "memory");                        \
    __builtin_amdgcn_sched_barrier(0);                                        \
    __builtin_amdgcn_s_barrier();                                             \
    if (DO_STAGE) QKV_STAGE8(SLOT);                                           \
    __builtin_amdgcn_s_setprio(1);                                            \
    _Pragma("unroll") for (int mm = 4; mm < 8; ++mm)                          \
        _Pragma("unroll") for (int nn = 0; nn < 4; ++nn) MFMA1(mm, nn);       \
    __builtin_amdgcn_s_setprio(0);                                            \
    __builtin_amdgcn_sched_barrier(0);                                        \
  } while (0)

  // prologue: stage subtiles 0,1 (16 loads in flight)
  QKV_STAGE8(0);
  QKV_STAGE8(1);

  // subtiles 0..5 stage s+2; 6,7 drain
  for (int i = 0; i < 3; ++i) {
    QKV_PHASE(0, 8, 1);
    QKV_PHASE(1, 8, 1);
  }
  QKV_PHASE(0, 8, 0);   // s=6
  QKV_PHASE(1, 0, 0);   // s=7

#undef QKV_PHASE
#undef MFMA1
#undef RD8
#undef QKV_STAGE8

  // epilogue: C fragment (row = base + (lane>>4)*4 + i, col = base + (lane&15))
  const int cr = lk4 << 2;
  const int z = bn >> 2;                       // 0=Q 1=K 2=V
  const int gr0 = bm * 256 + wm * 128;
  const int gc0 = (bn & 3) * 256 + wn * 64;
  if (z < 2) {
    unsigned short* C = (z == 0) ? Q : Kb;
#pragma unroll
    for (int m = 0; m < 8; ++m)
#pragma unroll
      for (int n = 0; n < 4; ++n)
#pragma unroll
        for (int i = 0; i < 4; ++i)
          C[(size_t)(gr0 + m * 16 + cr + i) * 1024 + (gc0 + n * 16 + lr)] =
              f32_to_bf16(acc[m][n][i]);
  } else {
    // Vt[b][d][t] = V[b*512+t][d]; 4 consecutive t per lane -> 8B store
#pragma unroll
    for (int m = 0; m < 8; ++m) {
      const int gr = gr0 + m * 16 + cr;
      const int b = gr >> 9, tt = gr & 511;
#pragma unroll
      for (int n = 0; n < 4; ++n) {
        const int d = gc0 + n * 16 + lr;
        US4 u;
        u.s[0] = f32_to_bf16(acc[m][n][0]);
        u.s[1] = f32_to_bf16(acc[m][n][1]);
        u.s[2] = f32_to_bf16(acc[m][n][2]);
        u.s[3] = f32_to_bf16(acc[m][n][3]);
        *(US4*)(Vt + ((size_t)b * 1024 + d) * 512 + tt) = u;
      }
    }
  }
}

// ---------------- shared BT-GEMM core (m97 structure + XOR swizzle) ----------
__device__ __forceinline__ void gemm_bt_core(const unsigned short* __restrict__ A,
                                             const unsigned short* __restrict__ B,
                                             int lda, int ldb, int K,
                                             unsigned short* As, unsigned short* Bs,
                                             f32x4 acc[4][4]) {
  const int tid = threadIdx.x;
  const int w = tid >> 6, lane = tid & 63;
  const int wr = w >> 1, wc = w & 1;
  const int lr = lane & 15;
  const int lk = (((lane >> 4) ^ ((lr >> 1) & 3))) << 3;
  const int k8 = (((lane & 3) ^ ((lane >> 3) & 3))) << 3;

  for (int kk = 0; kk < K; kk += 32) {
#pragma unroll
    for (int j = 0; j < 2; ++j) {
      const int i = (w << 1) + j;            // 0..7 wave-load id
      const int c = (i << 6) + lane;         // 16B chunk id, 512 per tile
      const int r = c >> 2;                  // tile row 0..127
      gload_lds16(A + (size_t)r * lda + kk + k8, As + (i << 9));
      gload_lds16(B + (size_t)r * ldb + kk + k8, Bs + (i << 9));
    }
    __syncthreads();                         // drains vmcnt for all waves
    bf16x8 av[4], bv[4];
#pragma unroll
    for (int m = 0; m < 4; ++m)
      av[m] = *(const bf16x8*)(As + (((wr << 6) + (m << 4) + lr) << 5) + lk);
#pragma unroll
    for (int n = 0; n < 4; ++n)
      bv[n] = *(const bf16x8*)(Bs + (((wc << 6) + (n << 4) + lr) << 5) + lk);
#pragma unroll
    for (int m = 0; m < 4; ++m)
#pragma unroll
      for (int n = 0; n < 4; ++n)
        acc[m][n] = __builtin_amdgcn_mfma_f32_16x16x32_bf16(av[m], bv[n], acc[m][n], 0, 0, 0);
    __syncthreads();
  }
}

// ---------------- S = Q K^T per batch (bf16 out) ----------------
__global__ __launch_bounds__(256) void s_gemm(const unsigned short* __restrict__ Q,
                                              const unsigned short* __restrict__ Kb,
                                              unsigned short* __restrict__ S) {
  __shared__ unsigned short As[4096];
  __shared__ unsigned short Bs[4096];
  const int bn = blockIdx.x, bm = blockIdx.y, b = blockIdx.z;
  const unsigned short* A = Q + ((size_t)b * 512 + bm * 128) * 1024;
  const unsigned short* B = Kb + ((size_t)b * 512 + bn * 128) * 1024;
  f32x4 acc[4][4] = {};
  gemm_bt_core(A, B, 1024, 1024, 1024, As, Bs, acc);

  const int tid = threadIdx.x;
  const int w = tid >> 6, lane = tid & 63;
  const int wr = w >> 1, wc = w & 1;
  const int cr = (lane >> 4) << 2;
  const int cc = lane & 15;
  unsigned short* Cp = S + (size_t)b * 262144;
  const int rbase = bm * 128 + wr * 64;
  const int cbase = bn * 128 + wc * 64;
#pragma unroll
  for (int m = 0; m < 4; ++m)
#pragma unroll
    for (int n = 0; n < 4; ++n)
#pragma unroll
      for (int i = 0; i < 4; ++i)
        Cp[(size_t)(rbase + m * 16 + cr + i) * 512 + (cbase + n * 16 + cc)] =
            f32_to_bf16(acc[m][n][i]);
}

// ---------------- row L2-normalize + softmax; write attn f32 + P bf16 -------
__global__ __launch_bounds__(256) void softmax_rows(const unsigned short* __restrict__ S,
                                                    float* __restrict__ out,
                                                    unsigned short* __restrict__ P) {
  const int w = threadIdx.x >> 6, lane = threadIdx.x & 63;
  const int r = blockIdx.x * 4 + w;          // global row 0..16383
  const int b = r >> 9, s = r & 511;
  US8 v = *(const US8*)(S + (size_t)r * 512 + lane * 8);
  float x[8];
#pragma unroll
  for (int i = 0; i < 8; ++i) x[i] = bf16_to_f32(v.s[i]);
  float ss = 0.f;
#pragma unroll
  for (int i = 0; i < 8; ++i) ss += x[i] * x[i];
  ss = wave_sum(ss);
  const float inv = 1.0f / fmaxf(sqrtf(ss), 1e-12f);
  float mx = -1e30f;
#pragma unroll
  for (int i = 0; i < 8; ++i) { x[i] *= inv; mx = fmaxf(mx, x[i]); }
  mx = wave_max(mx);
  float se = 0.f;
#pragma unroll
  for (int i = 0; i < 8; ++i) { x[i] = __expf(x[i] - mx); se += x[i]; }
  se = wave_sum(se);
  const float rs = 1.0f / se;
#pragma unroll
  for (int i = 0; i < 8; ++i) x[i] *= rs;

  float* op = out + (size_t)b * 786432 + 524288 + (size_t)s * 512 + lane * 8;
  float4 o0 = {x[0], x[1], x[2], x[3]};
  float4 o1 = {x[4], x[5], x[6], x[7]};
  *(float4*)op = o0;
  *(float4*)(op + 4) = o1;
  US8 u;
#pragma unroll
  for (int i = 0; i < 8; ++i) u.s[i] = f32_to_bf16(x[i]);
  *(US8*)(P + (size_t)r * 512 + lane * 8) = u;
}

// ---------------- O = P * V (via Vt, BT layout), bf16 out ----------------
__global__ __launch_bounds__(256) void pv_gemm(const unsigned short* __restrict__ P,
                                               const unsigned short* __restrict__ Vt,
                                               unsigned short* __restrict__ O) {
  __shared__ unsigned short As[4096];
  __shared__ unsigned short Bs[4096];
  const int bn = blockIdx.x, bm = blockIdx.y, b = blockIdx.z;
  const unsigned short* A = P + ((size_t)b * 512 + bm * 128) * 512;
  const unsigned short* B = Vt + ((size_t)b * 1024 + bn * 128) * 512;
  f32x4 acc[4][4] = {};
  gemm_bt_core(A, B, 512, 512, 512, As, Bs, acc);

  const int tid = threadIdx.x;
  const int w = tid >> 6, lane = tid & 63;
  const int wr = w >> 1, wc = w & 1;
  const int cr = (lane >> 4) << 2;
  const int cc = lane & 15;
  const int grow = b * 512 + bm * 128 + wr * 64;
  const int cbase = bn * 128 + wc * 64;
#pragma unroll
  for (int m = 0; m < 4; ++m)
#pragma unroll
    for (int n = 0; n < 4; ++n)
#pragma unroll
      for (int i = 0; i < 4; ++i)
        O[(size_t)(grow + m * 16 + cr + i) * 1024 + (cbase + n * 16 + cc)] =
            f32_to_bf16(acc[m][n][i]);
}

// ---------------- residual + LayerNorm, wave per row ----------------
__global__ __launch_bounds__(256) void ln_rows(const unsigned short* __restrict__ O,
                                               const unsigned short* __restrict__ Xb,
                                               const float* __restrict__ gamma,
                                               const float* __restrict__ beta,
                                               float* __restrict__ out) {
  const int w = threadIdx.x >> 6, lane = threadIdx.x & 63;
  const int r = blockIdx.x * 4 + w;
  const int b = r >> 9, s = r & 511;
  const unsigned short* orow = O + (size_t)r * 1024;
  const unsigned short* drow = Xb + (size_t)r * 1024;
  float x[16];
  float sm = 0.f, sq = 0.f;
#pragma unroll
  for (int j = 0; j < 4; ++j) {
    const int col = j * 256 + lane * 4;
    US4 o4 = *(const US4*)(orow + col);
    US4 d4 = *(const US4*)(drow + col);
    x[j * 4 + 0] = bf16_to_f32(o4.s[0]) + bf16_to_f32(d4.s[0]);
    x[j * 4 + 1] = bf16_to_f32(o4.s[1]) + bf16_to_f32(d4.s[1]);
    x[j * 4 + 2] = bf16_to_f32(o4.s[2]) + bf16_to_f32(d4.s[2]);
    x[j * 4 + 3] = bf16_to_f32(o4.s[3]) + bf16_to_f32(d4.s[3]);
  }
#pragma unroll
  for (int i = 0; i < 16; ++i) { sm += x[i]; sq += x[i] * x[i]; }
  sm = wave_sum(sm);
  sq = wave_sum(sq);
  const float mean = sm * (1.0f / 1024.0f);
  const float var = sq * (1.0f / 1024.0f) - mean * mean;
  const float rstd = rsqrtf(var + 1e-6f);
  float* op = out + (size_t)b * 786432 + (size_t)s * 1024;
#pragma unroll
  for (int j = 0; j < 4; ++j) {
    const int col = j * 256 + lane * 4;
    float4 g4 = *(const float4*)(gamma + col);
    float4 b4 = *(const float4*)(beta + col);
    float4 y;
    y.x = (x[j * 4 + 0] - mean) * rstd * g4.x + b4.x;
    y.y = (x[j * 4 + 1] - mean) * rstd * g4.y + b4.y;
    y.z = (x[j * 4 + 2] - mean) * rstd * g4.z + b4.z;
    y.w = (x[j * 4 + 3] - mean) * rstd * g4.w + b4.w;
    *(float4*)(op + col) = y;
  }
}

extern "C" void kernel_launch(void* const* d_in, const int* in_sizes, int n_in,
                              void* d_out, int out_size, void* d_ws, size_t ws_size,
                              hipStream_t stream) {
  const float* data  = (const float*)d_in[0];
  const float* wq    = (const float*)d_in[1];
  const float* wk    = (const float*)d_in[2];
  const float* wv    = (const float*)d_in[3];
  const float* gamma = (const float*)d_in[4];
  const float* beta  = (const float*)d_in[5];
  float* out = (float*)d_out;
  char* ws = (char*)d_ws;
  if (ws_size < WS_NEED) return;

  unsigned short* Xb = (unsigned short*)(ws + WS_XB);
  unsigned int*  Xf8 = (unsigned int*)(ws + WS_XF8);
  unsigned int*  Wf8 = (unsigned int*)(ws + WS_WF8);
  unsigned short* Q  = (unsigned short*)(ws + WS_Q);
  unsigned short* Kb = (unsigned short*)(ws + WS_K);
  unsigned short* Vt = (unsigned short*)(ws + WS_VT);
  unsigned short* S  = (unsigned short*)(ws + WS_S);
  unsigned short* P  = (unsigned short*)(ws + WS_P);
  unsigned short* O  = (unsigned short*)(ws + WS_O);

  cvt_data<<<8192, 256, 0, stream>>>(data, Xb, Xf8, 2097152);
  cvt_w3<<<dim3(512, 3), 256, 0, stream>>>(wq, wk, wv, Wf8);
  qkv_mx<<<768, 512, 0, stream>>>((const unsigned char*)Xf8, (const unsigned char*)Wf8,
                                  Q, Kb, Vt);
  s_gemm<<<dim3(4, 4, 32), 256, 0, stream>>>(Q, Kb, S);
  softmax_rows<<<4096, 256, 0, stream>>>(S, out, P);
  pv_gemm<<<dim3(8, 4, 32), 256, 0, stream>>>(P, Vt, O);
  ln_rows<<<4096, 256, 0, stream>>>(O, Xb, gamma, beta, out);
}